// Round 1
// baseline (148.968 us; speedup 1.0000x reference)
//
#include <hip/hip_runtime.h>
#include <hip/hip_bf16.h>

typedef float f32x4 __attribute__((ext_vector_type(4)));
typedef __bf16 bf16x8 __attribute__((ext_vector_type(8)));

union Frag { unsigned short h[8]; uint4 u4; bf16x8 b; };

__device__ __forceinline__ unsigned short f2bs(float f){
  __hip_bfloat16 v = __float2bfloat16(f);
  return __builtin_bit_cast(unsigned short, v);
}
__device__ __forceinline__ unsigned int pk2(float a, float b){
  return (unsigned int)f2bs(a) | ((unsigned int)f2bs(b) << 16);
}
__device__ __forceinline__ f32x4 relu4(f32x4 v){
  f32x4 r;
  #pragma unroll
  for (int j = 0; j < 4; ++j) r[j] = fmaxf(v[j], 0.f);
  return r;
}
__device__ __forceinline__ void pack2(Frag& dst, f32x4 a, f32x4 b){
  #pragma unroll
  for (int j = 0; j < 4; ++j){ dst.h[j] = f2bs(a[j]); dst.h[4+j] = f2bs(b[j]); }
}

// ---------------------------------------------------------------------------
// Prep: repack the 5 weight matrices into MFMA A-fragment order, bf16, in ws.
// Frag table: f in [0,64): W1 f=m*4+s (16), W2 16+m*2+s (8), MU 24+m*4+s (16),
// A1 40+m*4+s (16), A2 56+m*2+s (8). Each frag = 64 lanes x 16B.
// A-frag element e=(h,j): W[16*m + (lane&15)][32*s + 16*h + 4*(lane>>4) + j]
// ---------------------------------------------------------------------------
__global__ void prep_weights(const float* __restrict__ w1, const float* __restrict__ w2,
                             const float* __restrict__ mu, const float* __restrict__ a1,
                             const float* __restrict__ a2, uint4* __restrict__ ws){
  const int f = blockIdx.x;
  const int l = threadIdx.x;
  const float* W; int m, s, K;
  if (f < 16)      { W = w1; m = f >> 2;        s = f & 3;        K = 128; }
  else if (f < 24) { W = w2; m = (f - 16) >> 1; s = (f - 16) & 1; K = 64;  }
  else if (f < 40) { W = mu; m = (f - 24) >> 2; s = (f - 24) & 3; K = 128; }
  else if (f < 56) { W = a1; m = (f - 40) >> 2; s = (f - 40) & 3; K = 128; }
  else             { W = a2; m = (f - 56) >> 1; s = (f - 56) & 1; K = 64;  }
  const int row = 16 * m + (l & 15);
  const int k0  = 32 * s + 4 * (l >> 4);
  Frag fr;
  #pragma unroll
  for (int h = 0; h < 2; ++h)
    #pragma unroll
    for (int j = 0; j < 4; ++j)
      fr.h[4*h + j] = f2bs(W[row * K + k0 + 16*h + j]);
  ws[f * 64 + l] = fr.u4;
}

// ---------------------------------------------------------------------------
// Main: one block per node. 4 waves, 13 row-tiles of 16 neighbors.
// Per tile: gather -> S1(W1,relu) -> S2(W2,relu) -> S3(mu,sigmoid gate)
//           -> S4(att1,relu) -> S5(att2,relu) -> logit(att3)
// OG (gated) to LDS bf16; then block softmax + weighted sum.
// ---------------------------------------------------------------------------
#define LP 68   // padded OG row length in ushorts (64 dims + 4 pad)

__global__ __launch_bounds__(256)
void uv_agg_main(const int* __restrict__ nodes, const int* __restrict__ huv,
                 const int* __restrict__ hr, const float* __restrict__ u2e,
                 const float* __restrict__ v2e, const float* __restrict__ r2e,
                 const float* __restrict__ b1g, const float* __restrict__ b2g,
                 const float* __restrict__ bmg, const float* __restrict__ ba1g,
                 const float* __restrict__ ba2g, const float* __restrict__ a3g,
                 const uint4* __restrict__ wsfrag, float* __restrict__ out){
  __shared__ unsigned short og[208 * LP];
  __shared__ float lg[208];
  __shared__ float bias[6 * 64];
  __shared__ float red[8];
  __shared__ float psum[256];

  const int tid  = threadIdx.x;
  const int lane = tid & 63;
  const int wave = tid >> 6;
  const int g    = lane >> 4;
  const int r16  = lane & 15;
  const int n    = blockIdx.x;

  // stage biases + att3 weights into LDS
  for (int i = tid; i < 384; i += 256){
    const int w = i >> 6, d = i & 63;
    const float* src = (w==0)?b1g:(w==1)?b2g:(w==2)?bmg:(w==3)?ba1g:(w==4)?ba2g:a3g;
    bias[i] = src[d];
  }
  __syncthreads();

  // per-node q = v2e[nodes[n]]
  const int item = nodes[n];
  f32x4 qv[4];
  #pragma unroll
  for (int m = 0; m < 4; ++m)
    qv[m] = *(const f32x4*)(v2e + (size_t)item * 64 + 16*m + 4*g);
  Frag qf[2];
  #pragma unroll
  for (int s = 0; s < 2; ++s) pack2(qf[s], qv[2*s], qv[2*s+1]);
  f32x4 a3v[4];
  #pragma unroll
  for (int m = 0; m < 4; ++m)
    a3v[m] = *(const f32x4*)&bias[5*64 + 16*m + 4*g];

  for (int t = wave; t < 13; t += 4){
    const int rowbase = t * 16;
    const int r  = min(rowbase + r16, 199);
    const int iu = huv[n * 200 + r];
    const int ir = hr [n * 200 + r];

    // B0 = concat(e_uv, e_r) fragments (k 0..63 = u2e row, 64..127 = r2e row)
    Frag b0[4];
    const f32x4* urow = (const f32x4*)(u2e + (size_t)iu * 64);
    const f32x4* rrow = (const f32x4*)(r2e + (size_t)ir * 64);
    #pragma unroll
    for (int s = 0; s < 4; ++s){
      f32x4 va = (s < 2) ? urow[8*s + g]     : rrow[8*(s-2) + g];
      f32x4 vb = (s < 2) ? urow[8*s + 4 + g] : rrow[8*(s-2) + 4 + g];
      pack2(b0[s], va, vb);
    }

    // S1: X = relu(W1 @ B0 + b1)
    f32x4 X[4];
    #pragma unroll
    for (int m = 0; m < 4; ++m){
      f32x4 acc = *(const f32x4*)&bias[0*64 + 16*m + 4*g];
      #pragma unroll
      for (int s = 0; s < 4; ++s){
        Frag w; w.u4 = wsfrag[(m*4 + s) * 64 + lane];
        acc = __builtin_amdgcn_mfma_f32_16x16x32_bf16(w.b, b0[s].b, acc, 0, 0, 0);
      }
      X[m] = relu4(acc);
    }
    Frag bx[2];
    #pragma unroll
    for (int s = 0; s < 2; ++s) pack2(bx[s], X[2*s], X[2*s+1]);

    // S2: O = relu(W2 @ X + b2)
    f32x4 O[4];
    #pragma unroll
    for (int m = 0; m < 4; ++m){
      f32x4 acc = *(const f32x4*)&bias[1*64 + 16*m + 4*g];
      #pragma unroll
      for (int s = 0; s < 2; ++s){
        Frag w; w.u4 = wsfrag[(16 + m*2 + s) * 64 + lane];
        acc = __builtin_amdgcn_mfma_f32_16x16x32_bf16(w.b, bx[s].b, acc, 0, 0, 0);
      }
      O[m] = relu4(acc);
    }
    Frag bo[2];
    #pragma unroll
    for (int s = 0; s < 2; ++s) pack2(bo[s], O[2*s], O[2*s+1]);

    // S3: g = sigmoid(MU @ concat(O, q) + mu_b); OG = g*O + (1-g)*q
    f32x4 OG[4];
    #pragma unroll
    for (int m = 0; m < 4; ++m){
      f32x4 acc = *(const f32x4*)&bias[2*64 + 16*m + 4*g];
      #pragma unroll
      for (int s = 0; s < 4; ++s){
        Frag w; w.u4 = wsfrag[(24 + m*4 + s) * 64 + lane];
        acc = __builtin_amdgcn_mfma_f32_16x16x32_bf16(w.b, (s < 2) ? bo[s].b : qf[s-2].b, acc, 0, 0, 0);
      }
      f32x4 o_;
      #pragma unroll
      for (int j = 0; j < 4; ++j){
        float gg = 1.f / (1.f + __expf(-acc[j]));
        o_[j] = gg * O[m][j] + (1.f - gg) * qv[m][j];
      }
      OG[m] = o_;
    }
    // write OG tile to LDS (row = rowbase+r16, dims 16m+4g .. +3)
    {
      unsigned short* rowp = &og[(rowbase + r16) * LP];
      #pragma unroll
      for (int m = 0; m < 4; ++m){
        uint2 p; p.x = pk2(OG[m][0], OG[m][1]); p.y = pk2(OG[m][2], OG[m][3]);
        *(uint2*)&rowp[16*m + 4*g] = p;
      }
    }
    Frag bg[2];
    #pragma unroll
    for (int s = 0; s < 2; ++s) pack2(bg[s], OG[2*s], OG[2*s+1]);

    // S4: A1 = relu(ATT1 @ concat(OG, q) + att1_b)
    f32x4 A1[4];
    #pragma unroll
    for (int m = 0; m < 4; ++m){
      f32x4 acc = *(const f32x4*)&bias[3*64 + 16*m + 4*g];
      #pragma unroll
      for (int s = 0; s < 4; ++s){
        Frag w; w.u4 = wsfrag[(40 + m*4 + s) * 64 + lane];
        acc = __builtin_amdgcn_mfma_f32_16x16x32_bf16(w.b, (s < 2) ? bg[s].b : qf[s-2].b, acc, 0, 0, 0);
      }
      A1[m] = relu4(acc);
    }
    Frag b4[2];
    #pragma unroll
    for (int s = 0; s < 2; ++s) pack2(b4[s], A1[2*s], A1[2*s+1]);

    // S5: A2 = relu(ATT2 @ A1 + att2_b); logit = dot(att3_w, A2_row)
    float p = 0.f;
    #pragma unroll
    for (int m = 0; m < 4; ++m){
      f32x4 acc = *(const f32x4*)&bias[4*64 + 16*m + 4*g];
      #pragma unroll
      for (int s = 0; s < 2; ++s){
        Frag w; w.u4 = wsfrag[(56 + m*2 + s) * 64 + lane];
        acc = __builtin_amdgcn_mfma_f32_16x16x32_bf16(w.b, b4[s].b, acc, 0, 0, 0);
      }
      acc = relu4(acc);
      #pragma unroll
      for (int j = 0; j < 4; ++j) p += a3v[m][j] * acc[j];
    }
    p += __shfl_xor(p, 16);
    p += __shfl_xor(p, 32);
    if (lane < 16) lg[rowbase + lane] = p;
  }
  __syncthreads();

  // block softmax over 200 logits
  float x = (tid < 200) ? lg[tid] : -3.0e38f;
  float mx = x;
  #pragma unroll
  for (int o = 32; o; o >>= 1) mx = fmaxf(mx, __shfl_xor(mx, o));
  if (lane == 0) red[wave] = mx;
  __syncthreads();
  mx = fmaxf(fmaxf(red[0], red[1]), fmaxf(red[2], red[3]));
  float e = (tid < 200) ? __expf(x - mx) : 0.f;
  float sm = e;
  #pragma unroll
  for (int o = 32; o; o >>= 1) sm += __shfl_xor(sm, o);
  if (lane == 0) red[4 + wave] = sm;
  if (tid < 200) lg[tid] = e;
  __syncthreads();
  const float inv = 1.f / (red[4] + red[5] + red[6] + red[7]);

  // weighted sum: out[n][d] = sum_l w_l * OG[l][d]
  const int d = tid & 63, part = tid >> 6;
  float acc = 0.f;
  for (int l = part; l < 200; l += 4){
    unsigned int bits = og[l * LP + d];
    acc += lg[l] * __builtin_bit_cast(float, bits << 16);
  }
  psum[tid] = acc;
  __syncthreads();
  if (tid < 64){
    float o4 = psum[tid] + psum[64 + tid] + psum[128 + tid] + psum[192 + tid];
    out[(size_t)n * 64 + tid] = o4 * inv;
  }
}

extern "C" void kernel_launch(void* const* d_in, const int* in_sizes, int n_in,
                              void* d_out, int out_size, void* d_ws, size_t ws_size,
                              hipStream_t stream){
  const int*   nodes = (const int*)  d_in[0];
  const int*   huv   = (const int*)  d_in[1];
  const int*   hr    = (const int*)  d_in[2];
  const float* u2e   = (const float*)d_in[3];
  const float* v2e   = (const float*)d_in[4];
  const float* r2e   = (const float*)d_in[5];
  const float* w1    = (const float*)d_in[6];
  const float* b1    = (const float*)d_in[7];
  const float* w2    = (const float*)d_in[8];
  const float* b2    = (const float*)d_in[9];
  const float* muw   = (const float*)d_in[10];
  const float* mub   = (const float*)d_in[11];
  const float* a1w   = (const float*)d_in[12];
  const float* a1b   = (const float*)d_in[13];
  const float* a2w   = (const float*)d_in[14];
  const float* a2b   = (const float*)d_in[15];
  const float* a3w   = (const float*)d_in[16];
  // d_in[17] = att3_b: constant added to every logit -> cancels in softmax.

  const int N = in_sizes[0];            // 2048
  uint4* ws = (uint4*)d_ws;             // needs 64 KiB

  hipLaunchKernelGGL(prep_weights, dim3(64), dim3(64), 0, stream,
                     w1, w2, muw, a1w, a2w, ws);
  hipLaunchKernelGGL(uv_agg_main, dim3(N), dim3(256), 0, stream,
                     nodes, huv, hr, u2e, v2e, r2e,
                     b1, b2, mub, a1b, a2b, a3w,
                     (const uint4*)ws, (float*)d_out);
}

// Round 2
// 119.187 us; speedup vs baseline: 1.2499x; 1.2499x over previous
//
#include <hip/hip_runtime.h>
#include <hip/hip_bf16.h>

typedef float f32x4 __attribute__((ext_vector_type(4)));
typedef __bf16 bf16x8 __attribute__((ext_vector_type(8)));

union Frag { unsigned short h[8]; uint4 u4; bf16x8 b; };

__device__ __forceinline__ unsigned short f2bs(float f){
  __hip_bfloat16 v = __float2bfloat16(f);
  return __builtin_bit_cast(unsigned short, v);
}
__device__ __forceinline__ f32x4 relu4(f32x4 v){
  f32x4 r;
  #pragma unroll
  for (int j = 0; j < 4; ++j) r[j] = fmaxf(v[j], 0.f);
  return r;
}
__device__ __forceinline__ void pack2(Frag& dst, f32x4 a, f32x4 b){
  #pragma unroll
  for (int j = 0; j < 4; ++j){ dst.h[j] = f2bs(a[j]); dst.h[4+j] = f2bs(b[j]); }
}

// ---------------------------------------------------------------------------
// Prep: repack the 5 weight matrices into MFMA A-fragment order, bf16, in ws.
// Frag f: W1 f=m*4+s (16), W2 16+m*2+s (8), MU 24+m*4+s (16),
// A1 40+m*4+s (16), A2 56+m*2+s (8). Each frag = 64 lanes x 16B.
// A-frag element (h,j): W[16*m + (lane&15)][32*s + 16*h + 4*(lane>>4) + j]
// ---------------------------------------------------------------------------
__global__ void prep_weights(const float* __restrict__ w1, const float* __restrict__ w2,
                             const float* __restrict__ mu, const float* __restrict__ a1,
                             const float* __restrict__ a2, uint4* __restrict__ ws){
  const int f = blockIdx.x;
  const int l = threadIdx.x;
  const float* W; int m, s, K;
  if (f < 16)      { W = w1; m = f >> 2;        s = f & 3;        K = 128; }
  else if (f < 24) { W = w2; m = (f - 16) >> 1; s = (f - 16) & 1; K = 64;  }
  else if (f < 40) { W = mu; m = (f - 24) >> 2; s = (f - 24) & 3; K = 128; }
  else if (f < 56) { W = a1; m = (f - 40) >> 2; s = (f - 40) & 3; K = 128; }
  else             { W = a2; m = (f - 56) >> 1; s = (f - 56) & 1; K = 64;  }
  const int row = 16 * m + (l & 15);
  const int k0  = 32 * s + 4 * (l >> 4);
  Frag fr;
  #pragma unroll
  for (int h = 0; h < 2; ++h)
    #pragma unroll
    for (int j = 0; j < 4; ++j)
      fr.h[4*h + j] = f2bs(W[row * K + k0 + 16*h + j]);
  ws[f * 64 + l] = fr.u4;
}

// ---------------------------------------------------------------------------
// Main: one block per node, 4 waves, 13 row-tiles of 16 neighbors.
// Weights staged in LDS once per block (64KB). Online softmax: the gated
// rep OG never leaves registers; per-wave running (m, s, acc) merged at end.
// Next tile's u2e gather + indices prefetched into registers.
// LDS layout (dynamic, 68128 B):
//   [0,65536)      uint4 wlds[4096]   weight frags
//   [65536,67072)  float bias[384]    b1,b2,mu_b,att1_b,att2_b,att3_w
//   [67072,68096)  float wacc[256]    per-wave weighted sums
//   [68096,68112)  float wm[4]        per-wave running max
//   [68112,68128)  float wsum[4]      per-wave running denom
// ---------------------------------------------------------------------------
__global__ __launch_bounds__(256)
void uv_agg_main(const int* __restrict__ nodes, const int* __restrict__ huv,
                 const int* __restrict__ hr, const float* __restrict__ u2e,
                 const float* __restrict__ v2e, const float* __restrict__ r2e,
                 const float* __restrict__ b1g, const float* __restrict__ b2g,
                 const float* __restrict__ bmg, const float* __restrict__ ba1g,
                 const float* __restrict__ ba2g, const float* __restrict__ a3g,
                 const uint4* __restrict__ wsfrag, float* __restrict__ out){
  extern __shared__ unsigned char smem[];
  uint4* wlds = (uint4*)smem;
  float* bias = (float*)(smem + 65536);
  float* wacc = (float*)(smem + 67072);
  float* wmv  = (float*)(smem + 68096);
  float* wsv  = (float*)(smem + 68112);

  const int tid  = threadIdx.x;
  const int lane = tid & 63;
  const int wave = tid >> 6;
  const int g    = lane >> 4;
  const int r16  = lane & 15;
  const int n    = blockIdx.x;

  // stage weight frag table (64KB) into LDS
  #pragma unroll 4
  for (int i = tid; i < 4096; i += 256) wlds[i] = wsfrag[i];
  // stage biases + att3 weights
  for (int i = tid; i < 384; i += 256){
    const int w = i >> 6, d = i & 63;
    const float* src = (w==0)?b1g:(w==1)?b2g:(w==2)?bmg:(w==3)?ba1g:(w==4)?ba2g:a3g;
    bias[i] = src[d];
  }
  __syncthreads();

  // per-node q = v2e[nodes[n]]
  const int item = nodes[n];
  f32x4 qv[4];
  #pragma unroll
  for (int m = 0; m < 4; ++m)
    qv[m] = *(const f32x4*)(v2e + (size_t)item * 64 + 16*m + 4*g);
  Frag qf[2];
  #pragma unroll
  for (int s = 0; s < 2; ++s) pack2(qf[s], qv[2*s], qv[2*s+1]);

  // per-wave online softmax state
  float mw = -3.0e38f, sw = 0.f;
  f32x4 accw[4];
  #pragma unroll
  for (int m = 0; m < 4; ++m) accw[m] = (f32x4)(0.f);

  // prefetch first tile's gather
  int iu, ir;
  f32x4 ur[4];
  {
    const int r = min(wave * 16 + r16, 199);
    iu = huv[n * 200 + r]; ir = hr[n * 200 + r];
    const f32x4* urow = (const f32x4*)(u2e + (size_t)iu * 64);
    #pragma unroll
    for (int s = 0; s < 4; ++s) ur[s] = urow[4*s + g];
  }

  for (int t = wave; t < 13; t += 4){
    const int rowbase = t * 16;
    const bool valid = (rowbase + r16) < 200;

    // B0 = concat(e_uv, e_r) fragments
    const f32x4* rrow = (const f32x4*)(r2e + (size_t)ir * 64);
    f32x4 rr[4];
    #pragma unroll
    for (int s = 0; s < 4; ++s) rr[s] = rrow[4*s + g];
    Frag b0[4];
    pack2(b0[0], ur[0], ur[1]); pack2(b0[1], ur[2], ur[3]);
    pack2(b0[2], rr[0], rr[1]); pack2(b0[3], rr[2], rr[3]);

    // prefetch next tile (independent of this tile's chain)
    const int tn = t + 4;
    int iun = iu, irn = ir;
    f32x4 urn[4];
    #pragma unroll
    for (int s = 0; s < 4; ++s) urn[s] = ur[s];
    if (tn < 13){
      const int rn = min(tn * 16 + r16, 199);
      iun = huv[n * 200 + rn]; irn = hr[n * 200 + rn];
      const f32x4* urown = (const f32x4*)(u2e + (size_t)iun * 64);
      #pragma unroll
      for (int s = 0; s < 4; ++s) urn[s] = urown[4*s + g];
    }

    // S1: X = relu(W1 @ B0 + b1)
    f32x4 X[4];
    #pragma unroll
    for (int m = 0; m < 4; ++m){
      f32x4 acc = *(const f32x4*)&bias[0*64 + 16*m + 4*g];
      #pragma unroll
      for (int s = 0; s < 4; ++s){
        Frag w; w.u4 = wlds[(m*4 + s) * 64 + lane];
        acc = __builtin_amdgcn_mfma_f32_16x16x32_bf16(w.b, b0[s].b, acc, 0, 0, 0);
      }
      X[m] = relu4(acc);
    }
    Frag bx[2];
    #pragma unroll
    for (int s = 0; s < 2; ++s) pack2(bx[s], X[2*s], X[2*s+1]);

    // S2: O = relu(W2 @ X + b2)
    f32x4 O[4];
    #pragma unroll
    for (int m = 0; m < 4; ++m){
      f32x4 acc = *(const f32x4*)&bias[1*64 + 16*m + 4*g];
      #pragma unroll
      for (int s = 0; s < 2; ++s){
        Frag w; w.u4 = wlds[(16 + m*2 + s) * 64 + lane];
        acc = __builtin_amdgcn_mfma_f32_16x16x32_bf16(w.b, bx[s].b, acc, 0, 0, 0);
      }
      O[m] = relu4(acc);
    }
    Frag bo[2];
    #pragma unroll
    for (int s = 0; s < 2; ++s) pack2(bo[s], O[2*s], O[2*s+1]);

    // S3: gate = sigmoid(MU @ concat(O, q) + mu_b); OG = gate*O + (1-gate)*q
    f32x4 OG[4];
    #pragma unroll
    for (int m = 0; m < 4; ++m){
      f32x4 acc = *(const f32x4*)&bias[2*64 + 16*m + 4*g];
      #pragma unroll
      for (int s = 0; s < 4; ++s){
        Frag w; w.u4 = wlds[(24 + m*4 + s) * 64 + lane];
        acc = __builtin_amdgcn_mfma_f32_16x16x32_bf16(w.b, (s < 2) ? bo[s].b : qf[s-2].b, acc, 0, 0, 0);
      }
      #pragma unroll
      for (int j = 0; j < 4; ++j){
        float gg = 1.f / (1.f + __expf(-acc[j]));
        OG[m][j] = gg * O[m][j] + (1.f - gg) * qv[m][j];
      }
    }
    Frag bg[2];
    #pragma unroll
    for (int s = 0; s < 2; ++s) pack2(bg[s], OG[2*s], OG[2*s+1]);

    // S4: A1 = relu(ATT1 @ concat(OG, q) + att1_b)
    f32x4 A1[4];
    #pragma unroll
    for (int m = 0; m < 4; ++m){
      f32x4 acc = *(const f32x4*)&bias[3*64 + 16*m + 4*g];
      #pragma unroll
      for (int s = 0; s < 4; ++s){
        Frag w; w.u4 = wlds[(40 + m*4 + s) * 64 + lane];
        acc = __builtin_amdgcn_mfma_f32_16x16x32_bf16(w.b, (s < 2) ? bg[s].b : qf[s-2].b, acc, 0, 0, 0);
      }
      A1[m] = relu4(acc);
    }
    Frag b4[2];
    #pragma unroll
    for (int s = 0; s < 2; ++s) pack2(b4[s], A1[2*s], A1[2*s+1]);

    // S5: A2 = relu(ATT2 @ A1 + att2_b); logit = dot(att3_w, A2_row)
    float p = 0.f;
    #pragma unroll
    for (int m = 0; m < 4; ++m){
      f32x4 acc = *(const f32x4*)&bias[4*64 + 16*m + 4*g];
      #pragma unroll
      for (int s = 0; s < 2; ++s){
        Frag w; w.u4 = wlds[(56 + m*2 + s) * 64 + lane];
        acc = __builtin_amdgcn_mfma_f32_16x16x32_bf16(w.b, b4[s].b, acc, 0, 0, 0);
      }
      acc = relu4(acc);
      const f32x4 a3m = *(const f32x4*)&bias[5*64 + 16*m + 4*g];
      #pragma unroll
      for (int j = 0; j < 4; ++j) p += a3m[j] * acc[j];
    }
    p += __shfl_xor(p, 16);
    p += __shfl_xor(p, 32);          // every lane: logit of its own row

    // online softmax update (mask padded rows of tile 12)
    float pm = valid ? p : -3.0e38f;
    #pragma unroll
    for (int o = 1; o < 16; o <<= 1) pm = fmaxf(pm, __shfl_xor(pm, o));
    const float mnew = fmaxf(mw, pm);
    const float sc   = __expf(mw - mnew);
    const float e    = valid ? __expf(p - mnew) : 0.f;
    float es = e;
    #pragma unroll
    for (int o = 1; o < 16; o <<= 1) es += __shfl_xor(es, o);
    sw = sw * sc + es;
    mw = mnew;
    #pragma unroll
    for (int m = 0; m < 4; ++m)
      #pragma unroll
      for (int j = 0; j < 4; ++j)
        accw[m][j] = accw[m][j] * sc + e * OG[m][j];

    // rotate prefetch
    iu = iun; ir = irn;
    #pragma unroll
    for (int s = 0; s < 4; ++s) ur[s] = urn[s];
  }

  // per-wave: reduce acc over the 16 rows (r16 lanes), publish to LDS
  #pragma unroll
  for (int m = 0; m < 4; ++m)
    #pragma unroll
    for (int o = 1; o < 16; o <<= 1)
      #pragma unroll
      for (int j = 0; j < 4; ++j)
        accw[m][j] += __shfl_xor(accw[m][j], o);
  if (r16 == 0){
    #pragma unroll
    for (int m = 0; m < 4; ++m)
      *(f32x4*)&wacc[wave * 64 + 16*m + 4*g] = accw[m];
  }
  if (lane == 0){ wmv[wave] = mw; wsv[wave] = sw; }
  __syncthreads();

  // combine 4 waves, normalize, store
  if (tid < 64){
    const float M = fmaxf(fmaxf(wmv[0], wmv[1]), fmaxf(wmv[2], wmv[3]));
    const float e0 = __expf(wmv[0] - M), e1 = __expf(wmv[1] - M);
    const float e2 = __expf(wmv[2] - M), e3 = __expf(wmv[3] - M);
    const float tot = wsv[0]*e0 + wsv[1]*e1 + wsv[2]*e2 + wsv[3]*e3;
    const float v = wacc[tid]*e0 + wacc[64 + tid]*e1 + wacc[128 + tid]*e2 + wacc[192 + tid]*e3;
    out[(size_t)n * 64 + tid] = v / tot;
  }
}

extern "C" void kernel_launch(void* const* d_in, const int* in_sizes, int n_in,
                              void* d_out, int out_size, void* d_ws, size_t ws_size,
                              hipStream_t stream){
  const int*   nodes = (const int*)  d_in[0];
  const int*   huv   = (const int*)  d_in[1];
  const int*   hr    = (const int*)  d_in[2];
  const float* u2e   = (const float*)d_in[3];
  const float* v2e   = (const float*)d_in[4];
  const float* r2e   = (const float*)d_in[5];
  const float* w1    = (const float*)d_in[6];
  const float* b1    = (const float*)d_in[7];
  const float* w2    = (const float*)d_in[8];
  const float* b2    = (const float*)d_in[9];
  const float* muw   = (const float*)d_in[10];
  const float* mub   = (const float*)d_in[11];
  const float* a1w   = (const float*)d_in[12];
  const float* a1b   = (const float*)d_in[13];
  const float* a2w   = (const float*)d_in[14];
  const float* a2b   = (const float*)d_in[15];
  const float* a3w   = (const float*)d_in[16];
  // d_in[17] = att3_b: constant logit offset -> cancels in softmax.

  const int N = in_sizes[0];            // 2048
  uint4* ws = (uint4*)d_ws;             // 64 KiB frag table

  hipLaunchKernelGGL(prep_weights, dim3(64), dim3(64), 0, stream,
                     w1, w2, muw, a1w, a2w, ws);
  hipLaunchKernelGGL(uv_agg_main, dim3(N), dim3(256), 68128, stream,
                     nodes, huv, hr, u2e, v2e, r2e,
                     b1, b2, mub, a1b, a2b, a3w,
                     (const uint4*)ws, (float*)d_out);
}